// Round 7
// baseline (787.751 us; speedup 1.0000x reference)
//
#include <hip/hip_runtime.h>
#include <cstdint>
#include <cfloat>

// ---------------------------------------------------------------------------
// SimpleVQVAEEncoder, round 9: R6 skeleton (663 µs) + ILP + K-split.
//  - NPX=2: each lane owns 2 pixels -> per kk: 2 ds_read + 16 s_load + 32 FMA
//    (doubles FMA cover per weight s_load; residency is SGPR-capped at
//    ~2 blocks/CU so TLP can't grow — buy ILP instead).
//  - KSPLIT (conv2 x2, conv3 x4): blocks own K-segments, accumulate via
//    atomicAdd into outputs PRE-FILLED with bias (no extra workspace, no
//    reduce pass). ReLU between conv2/conv3 moves to conv3's staging read.
//  - Single-buffer 2-barrier loop, direct As[][] indexing (R1/R4/R5 taught:
//    any reg-prefetch restructure or LDS pointer blows up codegen 2-3x).
// ---------------------------------------------------------------------------

constexpr int B_    = 128;
constexpr int HW3   = 169;
constexpr int NPIXT = B_ * HW3;        // 21632
constexpr int NEMB  = 512;
constexpr int EMB   = 64;

// transpose weights [OC][K] -> [K][OC] (tiny prepass)
__global__ __launch_bounds__(256) void wtrans_kernel(
    const float* __restrict__ w, float* __restrict__ wt, int OC, int K)
{
    int idx = blockIdx.x * 256 + threadIdx.x;
    if (idx >= OC * K) return;
    int oc = idx / K, k = idx - oc * K;
    wt[(size_t)k * OC + oc] = w[idx];
}

// pre-fill an output tensor with its bias (for atomic K-split accumulation)
__global__ __launch_bounds__(256) void fill_bias_kernel(
    float* __restrict__ out, const float* __restrict__ b,
    int per_oc, int oc_count, int total)
{
    int i = blockIdx.x * 256 + threadIdx.x;
    if (i >= total) return;
    int oc = (i / per_oc) % oc_count;
    out[i] = b[oc];
}

template<int IC, int OC, int KH, int KW, int IH, int IW, int OH, int OW,
         int STRIDE, int PAD, bool RELU, bool TRANSOUT, int NPX, int KSPLIT,
         bool RELUIN>
__global__ __launch_bounds__(512) void conv_sgemm(
    const float* __restrict__ in, const float* __restrict__ wt,   // wt: [K][OC]
    const float* __restrict__ bias, float* __restrict__ out)
{
    constexpr int K    = IC * KH * KW;
    constexpr int KHW  = KH * KW;
    constexpr int BK   = 64;
    constexpr int KSEG = K / KSPLIT;
    static_assert(KSEG % BK == 0, "K segment must divide by BK");
    constexpr int NR   = BK / 8;           // rows staged per wave (8)
    constexpr int NOC  = OC / 8;           // oc per thread
    constexpr int MPX  = 64 * NPX;         // pixels per block
    constexpr int HWo  = OH * OW;

    __shared__ float As[BK][MPX];          // 32 KB at NPX=2

    const int tid  = threadIdx.x;
    const int lane = tid & 63;
    const int wv   = __builtin_amdgcn_readfirstlane(tid >> 6);  // force uniform
    const int oc0  = wv * NOC;
    const int ks      = blockIdx.x % KSPLIT;
    const int pixbase = (blockIdx.x / KSPLIT) * MPX;
    const int kbeg    = ks * KSEG;
    const int krow    = wv * NR;           // wave-uniform LDS row base

    // ---- hoisted per-pixel decomposition (once per thread, NPX pixels) ----
    int nn[NPX], hws[NPX], iyb[NPX], ixb[NPX];
    const float* inb[NPX];
#pragma unroll
    for (int s = 0; s < NPX; s++) {
        int pix = pixbase + s * 64 + lane;
        int n   = pix / HWo;
        int hw  = pix - n * HWo;
        int oy  = hw / OW;
        int ox  = hw - oy * OW;
        nn[s]  = n;  hws[s] = hw;
        iyb[s] = oy * STRIDE - PAD;
        ixb[s] = ox * STRIDE - PAD;
        inb[s] = in + (size_t)n * (IC * IH * IW);
    }

    float acc[NPX][NOC];
#pragma unroll
    for (int s = 0; s < NPX; s++)
#pragma unroll
        for (int j = 0; j < NOC; j++) acc[s][j] = 0.f;

    for (int t = 0; t < KSEG / BK; t++) {
        const int k0 = kbeg + t * BK;
        __syncthreads();               // previous iter's reads done
#pragma unroll
        for (int i = 0; i < NR; i++) {
            int kk = krow + i;                   // wave-uniform row
            int k  = k0 + kk;                    // uniform
            int ic = k / KHW;                    // uniform -> SALU
            int r  = k - ic * KHW;
            int ky = r / KW;
            int kx = r - ky * KW;
            int ch = ic * IH;                    // uniform
#pragma unroll
            for (int s = 0; s < NPX; s++) {
                int iy = iyb[s] + ky;            // per-lane: 1 add
                int ix = ixb[s] + kx;            // 1 add
                float v = 0.f;
                if ((unsigned)iy < (unsigned)IH && (unsigned)ix < (unsigned)IW)
                    v = inb[s][(ch + iy) * IW + ix];   // exec-masked load
                if (RELUIN) v = fmaxf(v, 0.f);
                As[kk][s * 64 + lane] = v;
            }
        }
        __syncthreads();

        const float* bp = wt + (size_t)k0 * OC + oc0;    // wave-uniform address
#pragma unroll
        for (int kk = 0; kk < BK; kk++) {
            float a[NPX];
#pragma unroll
            for (int s = 0; s < NPX; s++) a[s] = As[kk][s * 64 + lane];
#pragma unroll
            for (int j = 0; j < NOC; j++) {
                float w = bp[kk * OC + j];       // s_load, reused NPX times
#pragma unroll
                for (int s = 0; s < NPX; s++)
                    acc[s][j] = fmaf(a[s], w, acc[s][j]);
            }
        }
    }

    // epilogue
#pragma unroll
    for (int s = 0; s < NPX; s++) {
        int pix = pixbase + s * 64 + lane;
#pragma unroll
        for (int j = 0; j < NOC; j++) {
            int oc = oc0 + j;
            if (KSPLIT > 1) {                    // partial: accumulate (bias pre-filled)
                float v = acc[s][j];
                if (TRANSOUT) atomicAdd(&out[(size_t)oc * NPIXT + pix], v);
                else atomicAdd(&out[((size_t)(nn[s] * OC + oc)) * HWo + hws[s]], v);
            } else {
                float v = acc[s][j] + bias[oc];
                if (RELU) v = fmaxf(v, 0.f);
                if (TRANSOUT) out[(size_t)oc * NPIXT + pix] = v;
                else out[((size_t)(nn[s] * OC + oc)) * HWo + hws[s]] = v;
            }
        }
    }
}

// ---------------------------------------------------------------------------
// VQ: per pixel argmin over 512 codes of |z|^2 - 2 z.c + |c|^2.
// z transposed [64][21632] (bias already included). Codebook reads uniform.
// ---------------------------------------------------------------------------
__global__ __launch_bounds__(256) void vq_kernel(
    const float* __restrict__ zt,           // [64][21632]
    const float* __restrict__ cb,           // [512][64]
    unsigned long long* __restrict__ best)  // [21632], preset to ~0
{
    const int tid  = threadIdx.x;
    const int lane = tid & 63;
    const int wv   = tid >> 6;
    const int pg   = blockIdx.x >> 1;
    const int half = blockIdx.x & 1;
    const int p    = pg * 64 + lane;        // 338*64 == 21632 exactly

    __shared__ float c2s[256];
    {
        int code = half * 256 + tid;
        const float* c = cb + (size_t)code * EMB;
        float s = 0.f;
#pragma unroll
        for (int j = 0; j < EMB; j += 4) {
            float4 v = *(const float4*)(c + j);
            s = fmaf(v.x, v.x, s); s = fmaf(v.y, v.y, s);
            s = fmaf(v.z, v.z, s); s = fmaf(v.w, v.w, s);
        }
        c2s[tid] = s;
    }
    __syncthreads();

    float zr[EMB];
    float zz = 0.f;
#pragma unroll
    for (int j = 0; j < EMB; j++) {
        float v = zt[(size_t)j * NPIXT + p];
        zr[j] = v;
        zz = fmaf(v, v, zz);
    }

    float bestScore = FLT_MAX;
    int   bestIdx   = 0x7fffffff;
    const int base = half * 256 + wv * 64;
    for (int ci = 0; ci < 64; ci++) {
        int code = __builtin_amdgcn_readfirstlane(base + ci);
        const float* c = cb + (size_t)code * EMB;
        float dot = 0.f;
#pragma unroll
        for (int j = 0; j < EMB; j++) dot = fmaf(zr[j], c[j], dot);
        float score = fmaf(-2.f, dot, zz) + c2s[code - half * 256];
        if (score < bestScore) { bestScore = score; bestIdx = code; }
    }

    unsigned u = __float_as_uint(bestScore);
    u = (bestScore < 0.f) ? ~u : (u | 0x80000000u);
    unsigned long long pk = ((unsigned long long)u << 32) | (unsigned)bestIdx;
    atomicMin(&best[p], pk);
}

__global__ __launch_bounds__(256) void onehot_kernel(
    const unsigned long long* __restrict__ best, float* __restrict__ out)
{
    int p = blockIdx.x * 256 + threadIdx.x;
    if (p >= NPIXT) return;
    int code = (int)(unsigned)(best[p] & 0xffffffffu);
    int b  = p / HW3;
    int hw = p - b * HW3;
    out[((size_t)b * NEMB + code) * HW3 + hw] = 1.0f;
}

extern "C" void kernel_launch(void* const* d_in, const int* in_sizes, int n_in,
                              void* d_out, int out_size, void* d_ws, size_t ws_size,
                              hipStream_t stream) {
    const float* x  = (const float*)d_in[0];
    const float* w1 = (const float*)d_in[1];
    const float* b1 = (const float*)d_in[2];
    const float* w2 = (const float*)d_in[3];
    const float* b2 = (const float*)d_in[4];
    const float* w3 = (const float*)d_in[5];
    const float* b3 = (const float*)d_in[6];
    const float* cb = (const float*)d_in[7];
    float* out = (float*)d_out;

    float* z1  = (float*)d_ws;                            // 128*64*48*48   = 75.5 MB
    float* z2  = z1 + (size_t)128 * 64 * 48 * 48;         // 128*128*16*16  = 16.8 MB (raw, no relu)
    float* z3t = z2 + (size_t)128 * 128 * 16 * 16;        // [64][21632]    =  5.5 MB
    unsigned long long* best = (unsigned long long*)(z3t + (size_t)EMB * NPIXT);
    float* w1t = (float*)(best + NPIXT);                  // [192][64]
    float* w2t = w1t + 192 * 64;                          // [2304][128]
    float* w3t = w2t + 2304 * 128;                        // [2048][64]

    hipMemsetAsync(out, 0, (size_t)out_size * sizeof(float), stream);
    hipMemsetAsync(best, 0xFF, (size_t)NPIXT * sizeof(unsigned long long), stream);

    wtrans_kernel<<<(64 * 192 + 255) / 256, 256, 0, stream>>>(w1, w1t, 64, 192);
    wtrans_kernel<<<(128 * 2304 + 255) / 256, 256, 0, stream>>>(w2, w2t, 128, 2304);
    wtrans_kernel<<<(64 * 2048 + 255) / 256, 256, 0, stream>>>(w3, w3t, 64, 2048);

    // pre-fill K-split outputs with bias (atomic accumulation targets)
    constexpr int Z2TOT = 128 * 128 * 256;   // [n][oc][16*16]
    fill_bias_kernel<<<(Z2TOT + 255) / 256, 256, 0, stream>>>(z2, b2, 256, 128, Z2TOT);
    constexpr int Z3TOT = EMB * NPIXT;       // [oc][pix]
    fill_bias_kernel<<<(Z3TOT + 255) / 256, 256, 0, stream>>>(z3t, b3, NPIXT, EMB, Z3TOT);

    // conv1: 294912 px / 128 = 2304 blocks, K=192, store bias+relu
    conv_sgemm<3, 64, 8, 8, 192, 192, 48, 48, 4, 2, true, false, 2, 1, false>
        <<<294912 / 128, 512, 0, stream>>>(x, w1t, b1, z1);
    // conv2: 32768 px / 128 = 256 tiles x KSPLIT2 = 512 blocks; atomic, raw out
    conv_sgemm<64, 128, 6, 6, 48, 48, 16, 16, 3, 2, false, false, 2, 2, false>
        <<<(32768 / 128) * 2, 512, 0, stream>>>(z1, w2t, b2, z2);
    // conv3: 21632 px / 128 = 169 tiles x KSPLIT4 = 676 blocks; relu-on-read,
    // transposed atomic out
    conv_sgemm<128, 64, 4, 4, 16, 16, 13, 13, 1, 0, false, true, 2, 4, true>
        <<<(NPIXT / 128) * 4, 512, 0, stream>>>(z2, w3t, b3, z3t);

    vq_kernel<<<338 * 2, 256, 0, stream>>>(z3t, cb, best);
    onehot_kernel<<<(NPIXT + 255) / 256, 256, 0, stream>>>(best, out);
}